// Round 8
// baseline (190.303 us; speedup 1.0000x reference)
//
#include <hip/hip_runtime.h>
#include <math.h>

#define BB 4096
#define NN 256
#define FIN 15
#define HH 128
#define HH4 32
#define FOUT 6

typedef __attribute__((ext_vector_type(8))) short short8v;   // 8 bf16 in 4 VGPRs
typedef __attribute__((ext_vector_type(4))) float f32x4;

// fast silu/sigmoid: v_exp + v_rcp (no IEEE divide sequence)
__device__ __forceinline__ float silu_f(float z) {
    return z * __builtin_amdgcn_rcpf(1.0f + __expf(-z));
}
__device__ __forceinline__ float sigm_f(float z) {
    return __builtin_amdgcn_rcpf(1.0f + __expf(-z));
}

__device__ __forceinline__ unsigned short f2bf(float f) {
    unsigned int u = __builtin_bit_cast(unsigned int, f);
    u += 0x7FFFu + ((u >> 16) & 1u);      // round-to-nearest-even
    return (unsigned short)(u >> 16);
}

// pack 2 f32 -> 2 bf16 in one u32 (low = lo, high = hi)
__device__ __forceinline__ unsigned int cvt_pk_bf16(float lo, float hi) {
    unsigned int r;
    asm("v_cvt_pk_bf16_f32 %0, %1, %2" : "=v"(r) : "v"(lo), "v"(hi));
    return r;
}

// ---------------- prep: weights -> bf16 [n][k] in ws ----------------
// ws (ushort): w1t[128][32] @0 (k=0..14 data, 15..31 zero)
//              w2t[128][128] @4096, k PERMUTED to match h1 paired-column layout
__global__ void prep_kernel(const float* __restrict__ nW1,
                            const float* __restrict__ nW2,
                            unsigned short* __restrict__ ws) {
    const int idx = blockIdx.x * 256 + threadIdx.x;
    if (idx < 4096) {
        const int n = idx >> 5, k = idx & 31;
        ws[idx] = (k < FIN) ? f2bf(nW1[k * HH + n]) : (unsigned short)0;
    } else if (idx < 20480) {
        const int j = idx - 4096;
        const int n = j >> 7, kp = j & 127;
        // inverse of colpos: kp = 32*wvc + 2*lr + half  ->  k = 32*wvc + 16*half + lr
        const int k = 32 * (kp >> 5) + 16 * (kp & 1) + ((kp & 31) >> 1);
        ws[idx] = f2bf(nW2[k * HH + n]);
    }
}

#define MFMA16(A, B, C) __builtin_amdgcn_mfma_f32_16x16x32_bf16((A), (B), (C), 0, 0, 0)

__launch_bounds__(512)
__global__ void stargnn_kernel(
    const float* __restrict__ x_feat,   // (B,N,FIN)
    const float* __restrict__ coords,   // (B,N,3)
    const float* __restrict__ mask,     // (B,N,1)
    const int*   __restrict__ centers,  // (B,)
    const float* __restrict__ nb1, const float* __restrict__ nb2,
    const float* __restrict__ eW1, const float* __restrict__ eb1,
    const float* __restrict__ eW2, const float* __restrict__ eb2,
    const float* __restrict__ rW1, const float* __restrict__ rb1,
    const float* __restrict__ rW2, const float* __restrict__ rb2,
    const unsigned short* __restrict__ wbf,  // ws: w1t @0, w2t @4096
    float* __restrict__ out)            // (B,FOUT)
{
    const int b   = blockIdx.x;
    const int tid = threadIdx.x;
    const int wv  = tid >> 6;     // wave 0..7
    const int wvc = wv & 3;       // column-pair group: cols 32*wvc .. +31
    const int rh  = wv >> 2;      // row half of quarter: rows rh*32 .. +31
    const int l   = tid & 63;
    const int lr  = l & 15;
    const int lg  = l >> 4;

    const int col0 = wvc * 32 + lr;        // first owned column
    const int col1 = wvc * 32 + 16 + lr;   // second owned column

    // LDS ~28.7 KB -> 4 blocks/CU (32-wave cap)
    __shared__ __align__(16) unsigned short xbf[64 * 40];     // 5120 B
    __shared__ __align__(16) unsigned short h1bf[64 * 136];   // 17408 B (permuted cols)
    __shared__ __align__(16) float wns[NN];   // w_n*mask^2 (+ center delta)
    __shared__ float epart[NN];               // edge-MLP partial (terms 16..31)
    __shared__ float msgs[HH];
    __shared__ float part[2 * HH];            // cross-rh partials
    __shared__ float part4[4 * HH];           // readout split-K partials
    __shared__ float r1s[HH];

    const int c = centers[b];

    // ---- zero xbf once (cols 15..39 must stay 0) ----
    for (int i = tid; i < (64 * 40) / 2; i += 512)
        ((unsigned int*)xbf)[i] = 0u;

    // ---- edge MLP partial: all 8 waves, 16 terms each ----
    const int en = tid & 255;
    const int eh = tid >> 8;
    float es;
    {
        const float* cb = coords + (size_t)b * NN * 3;
        const float c0x = cb[c*3+0], c0y = cb[c*3+1], c0z = cb[c*3+2];
        const float dx = cb[en*3+0] - c0x;
        const float dy = cb[en*3+1] - c0y;
        const float dz = cb[en*3+2] - c0z;
        const float d  = sqrtf(dx*dx + dy*dy + dz*dz);
        es = (eh == 0) ? eb2[0] : 0.0f;
        #pragma unroll
        for (int i = 0; i < 16; ++i) {
            const int t = eh * 16 + i;
            float z = d * eW1[t] + eb1[t];
            es += silu_f(z) * eW2[t];
        }
        if (eh == 1) epart[en] = es;
    }
    __syncthreads();   // zerofill + epart ready

    // ---- finalize wns (waves 0..3) ----
    if (eh == 0) {
        const float m = mask[(size_t)b * NN + en];
        const float w = sigm_f(es + epart[en]);
        wns[en] = w * m * m + ((en == c) ? m : 0.0f);
    }

    // ---- bias-as-C-init vectors ----
    const float nb1c0 = nb1[col0], nb1c1 = nb1[col1];
    const float nb2c0 = nb2[col0], nb2c1 = nb2[col1];
    const f32x4 b1i0 = {nb1c0, nb1c0, nb1c0, nb1c0};
    const f32x4 b1i1 = {nb1c1, nb1c1, nb1c1, nb1c1};
    const f32x4 b2i0 = {nb2c0, nb2c0, nb2c0, nb2c0};
    const f32x4 b2i1 = {nb2c1, nb2c1, nb2c1, nb2c1};

    // ---- B-fragments (named registers, whole kernel) ----
    const short8v* w1tp = (const short8v*)wbf;            // [128][32]: idx = n*4 + lg
    const short8v* w2tp = (const short8v*)(wbf + 4096);   // [128][128] perm-k: idx = n*16 + kb*4 + lg
    const short8v b1f0 = w1tp[col0 * 4 + lg];
    const short8v b1f1 = w1tp[col1 * 4 + lg];
    const short8v b2f00 = w2tp[col0 * 16 + 0  + lg];
    const short8v b2f01 = w2tp[col0 * 16 + 4  + lg];
    const short8v b2f02 = w2tp[col0 * 16 + 8  + lg];
    const short8v b2f03 = w2tp[col0 * 16 + 12 + lg];
    const short8v b2f10 = w2tp[col1 * 16 + 0  + lg];
    const short8v b2f11 = w2tp[col1 * 16 + 4  + lg];
    const short8v b2f12 = w2tp[col1 * 16 + 8  + lg];
    const short8v b2f13 = w2tp[col1 * 16 + 12 + lg];

    float macc0 = 0.f, macc1 = 0.f;
    unsigned int* h1dw = (unsigned int*)h1bf;

    // ================= four quarters of 64 nodes =================
    for (int q = 0; q < 4; ++q) {
        // ---- stage x -> bf16 [64][40] via cvt_pk (threads < 256) ----
        // safe: previous quarter's xbf readers (layer1) passed the L1->L2 barrier
        if (tid < 256) {
            const int node = tid >> 2;          // 0..63
            const int kq   = tid & 3;           // k-quad 0..3
            const float* xr = x_feat + ((size_t)b * NN + q * 64 + node) * FIN + kq * 4;
            const float f0 = xr[0];
            const float f1 = xr[1];
            const float f2 = xr[2];
            const float f3 = (kq < 3) ? xr[3] : 0.0f;   // k=15 pad
            const unsigned int p0 = cvt_pk_bf16(f0, f1);
            const unsigned int p1 = cvt_pk_bf16(f2, f3);
            unsigned int* dst = (unsigned int*)&xbf[node * 40 + kq * 4];
            dst[0] = p0;
            dst[1] = p1;
        }
        __syncthreads();   // xbf ready; also fences prev-quarter h1bf reads (L2_q-1)

        // ---- layer 1: h1 = silu(x @ nW1 + nb1) -> permuted h1bf ----
        #pragma unroll
        for (int mi = 0; mi < 2; ++mi) {
            const int mt = rh * 2 + mi;        // row-tile within quarter (0..3)
            const short8v a = *(const short8v*)&xbf[(mt * 16 + lr) * 40 + lg * 8];
            f32x4 d0 = MFMA16(a, b1f0, b1i0);
            f32x4 d1 = MFMA16(a, b1f1, b1i1);
            #define H1W(r) { \
                const int row = mt * 16 + lg * 4 + (r); \
                h1dw[row * 68 + 16 * wvc + lr] = cvt_pk_bf16(silu_f(d0[r]), silu_f(d1[r])); }
            H1W(0) H1W(1) H1W(2) H1W(3)
            #undef H1W
        }
        __syncthreads();   // h1bf ready

        // ---- layer 2 MFMA + epilogue ----
        #pragma unroll
        for (int mi = 0; mi < 2; ++mi) {
            const int mt = rh * 2 + mi;
            const unsigned short* arow = &h1bf[(mt * 16 + lr) * 136 + lg * 8];
            const short8v a0 = *(const short8v*)(arow);
            const short8v a1 = *(const short8v*)(arow + 32);
            const short8v a2 = *(const short8v*)(arow + 64);
            const short8v a3 = *(const short8v*)(arow + 96);
            f32x4 acc0 = b2i0, acc1 = b2i1;
            acc0 = MFMA16(a0, b2f00, acc0);
            acc0 = MFMA16(a1, b2f01, acc0);
            acc0 = MFMA16(a2, b2f02, acc0);
            acc0 = MFMA16(a3, b2f03, acc0);
            acc1 = MFMA16(a0, b2f10, acc1);
            acc1 = MFMA16(a1, b2f11, acc1);
            acc1 = MFMA16(a2, b2f12, acc1);
            acc1 = MFMA16(a3, b2f13, acc1);

            const f32x4 mw4 = *(const f32x4*)&wns[q * 64 + mt * 16 + lg * 4];
            #define EPIR(r) { \
                macc0 += mw4[r] * silu_f(acc0[r]); \
                macc1 += mw4[r] * silu_f(acc1[r]); }
            EPIR(0) EPIR(1) EPIR(2) EPIR(3)
            #undef EPIR
        }
    }

    // ---- reduce msg: lanes (lg) via shfl, row-halves (rh) via LDS ----
    macc0 += __shfl_xor(macc0, 16);
    macc0 += __shfl_xor(macc0, 32);
    macc1 += __shfl_xor(macc1, 16);
    macc1 += __shfl_xor(macc1, 32);
    if (lg == 0) {
        part[rh * HH + col0] = macc0;
        part[rh * HH + col1] = macc1;
    }
    __syncthreads();

    if (tid < HH) msgs[tid] = part[tid] + part[HH + tid];
    __syncthreads();

    // ---- readout layer 1 (f32 VALU, split-K over 4 quarter groups) ----
    {
        const int j  = tid & 127;
        const int kq = tid >> 7;
        float acc = 0.f;
        #pragma unroll 8
        for (int k = kq * 32; k < kq * 32 + 32; ++k)
            acc += msgs[k] * rW1[k * HH + j];
        part4[kq * HH + j] = acc;
    }
    __syncthreads();
    if (tid < HH)
        r1s[tid] = silu_f(part4[tid] + part4[HH + tid] + part4[2 * HH + tid]
                          + part4[3 * HH + tid] + rb1[tid]);
    __syncthreads();

    // ---- final layer: 32 threads per output, shfl reduce ----
    if (tid < 32 * FOUT) {
        const int j  = tid >> 5;        // 0..5
        const int kk = tid & 31;        // 0..31
        float acc = 0.f;
        #pragma unroll
        for (int q = 0; q < 4; ++q) {
            const int k = kk * 4 + q;
            acc += r1s[k] * rW2[k * FOUT + j];
        }
        acc += __shfl_xor(acc, 1);
        acc += __shfl_xor(acc, 2);
        acc += __shfl_xor(acc, 4);
        acc += __shfl_xor(acc, 8);
        acc += __shfl_xor(acc, 16);
        if (kk == 0) out[(size_t)b * FOUT + j] = acc + rb2[j];
    }
}

extern "C" void kernel_launch(void* const* d_in, const int* in_sizes, int n_in,
                              void* d_out, int out_size, void* d_ws, size_t ws_size,
                              hipStream_t stream) {
    const float* x_feat = (const float*)d_in[0];
    const float* coords = (const float*)d_in[1];
    const float* mask   = (const float*)d_in[2];
    const int*   ctr    = (const int*)d_in[3];
    const float* nW1 = (const float*)d_in[4];
    const float* nb1 = (const float*)d_in[5];
    const float* nW2 = (const float*)d_in[6];
    const float* nb2 = (const float*)d_in[7];
    const float* eW1 = (const float*)d_in[8];
    const float* eb1 = (const float*)d_in[9];
    const float* eW2 = (const float*)d_in[10];
    const float* eb2 = (const float*)d_in[11];
    const float* rW1 = (const float*)d_in[12];
    const float* rb1 = (const float*)d_in[13];
    const float* rW2 = (const float*)d_in[14];
    const float* rb2 = (const float*)d_in[15];
    float* out = (float*)d_out;
    unsigned short* wbf = (unsigned short*)d_ws;

    prep_kernel<<<dim3(80), dim3(256), 0, stream>>>(nW1, nW2, wbf);
    stargnn_kernel<<<dim3(BB), dim3(512), 0, stream>>>(
        x_feat, coords, mask, ctr,
        nb1, nb2, eW1, eb1, eW2, eb2, rW1, rb1, rW2, rb2, wbf, out);
}